// Round 9
// baseline (424.726 us; speedup 1.0000x reference)
//
#include <hip/hip_runtime.h>

namespace {

constexpr int KK   = 7;
constexpr int PADC = 3;
constexpr int B = 8, C = 64, T = 32, H = 56, W = 56;

constexpr int ROWS = 8;                       // output rows per block
constexpr int NTHR = 448;                     // 7 dy * 8 q-chunks * 8 rows
constexpr int NBLK = B * T * (H / ROWS);      // 1792
constexpr int SLICE = H * W;                  // 3136
constexpr int CSTRIDE = T * SLICE;            // 100352 (channel stride in x)
constexpr int WSTRIDE = T * KK * KK;          // 1568   (channel stride in fw)
constexpr int NTOT = B * C * CSTRIDE;         // total floats in x

// 4B-aligned float4: global loads at arbitrary dword offsets.
typedef float f4 __attribute__((ext_vector_type(4), aligned(4)));

__global__ __launch_bounds__(NTHR, 1)
void corr_fwd(const float* __restrict__ x, const float* __restrict__ fw,
              float* __restrict__ out) {
  __shared__ float obuf[KK * ROWS * W];   // 3136 floats, epilogue only

  const int tid = threadIdx.x;
  const int dy  = tid % 7;
  const int q   = (tid / 7) % 8;
  const int r   = tid / 56;

  int blk = blockIdx.x;
  const int rt = blk % (H / ROWS); blk /= (H / ROWS);
  const int t  = blk % T;
  const int b  = blk / T;
  const int h0 = rt * ROWS;
  const int tp = (t > 0) ? (t - 1) : 0;

  // per-thread geometry (channel-invariant, hoisted)
  const int  zrow_raw = h0 + r + dy - PADC;
  const bool row_ok   = (zrow_raw >= 0) && (zrow_raw < H);
  const int  zrow     = zrow_raw < 0 ? 0 : (zrow_raw >= H ? H - 1 : zrow_raw);
  const unsigned mlo  = (q == 0) ? 0u : ~0u;   // window cols -3..-1 invalid
  const unsigned mhi  = (q == 7) ? 0u : ~0u;   // window cols 56..58 invalid

  // per-thread base offsets; channel adds a uniform c*STRIDE (SGPR-side)
  const int zoff = (b * C * T + t)  * SLICE + zrow * W + q * 7 - PADC;
  const int xoff = (b * C * T + tp) * SLICE + (h0 + r) * W + q * 7;
  const int woff = (t * KK + dy) * KK;

  float acc[7][7];
#pragma unroll
  for (int a = 0; a < 7; ++a)
#pragma unroll
    for (int e = 0; e < 7; ++e) acc[a][e] = 0.f;

  // ---- 4 named Z/X staging sets (depth-3 prefetch), W depth-1 A/B ----
  f4 Z0[3], Z1[3], Z2[3], Z3[3]; float z0e, z1e, z2e, z3e;
  f4 X0[2], X1[2], X2[2], X3[2];
  f4 WAa, WAb, WBa, WBb;

  auto loadZX = [&](f4 (&Z)[3], float& ze, f4 (&X)[2], int c) {
    c = c > C - 1 ? C - 1 : c;                 // clamp: dummy tail prefetches
    const int zi = zoff + c * CSTRIDE;
    if (c == 0 || c == C - 1) {                // only channels that can leave x
#pragma unroll
      for (int j = 0; j < 12; ++j) {
        int fi = zi + j;
        fi = fi < 0 ? 0 : (fi > NTOT - 1 ? NTOT - 1 : fi);
        Z[j / 4][j % 4] = x[fi];               // static reg index (unrolled)
      }
      int fi = zi + 12;
      fi = fi < 0 ? 0 : (fi > NTOT - 1 ? NTOT - 1 : fi);
      ze = x[fi];
    } else {
      const f4* p = reinterpret_cast<const f4*>(x + zi);
      Z[0] = p[0]; Z[1] = p[1]; Z[2] = p[2];
      ze = x[zi + 12];
    }
    const f4* px = reinterpret_cast<const f4*>(x + xoff + c * CSTRIDE);
    X[0] = px[0]; X[1] = px[1];                // always in-bounds (tp <= 30)
  };
  auto loadW = [&](f4& wa, f4& wb, int c) {
    c = c > C - 1 ? C - 1 : c;
    wa = *reinterpret_cast<const f4*>(fw + woff + c * WSTRIDE);      // w[0..3]
    wb = *reinterpret_cast<const f4*>(fw + woff + c * WSTRIDE + 3);  // w[3..6]
  };
  auto maskf = [](float v, unsigned m) {
    return __uint_as_float(__float_as_uint(v) & m);
  };

  auto compute = [&](const f4 (&Z)[3], float ze, const f4 (&X)[2],
                     f4 wa, f4 wb) {
    if (row_ok) {   // exec-masked: OOB-row lanes keep acc == 0
      const float zz[13] = {
          maskf(Z[0][0], mlo), maskf(Z[0][1], mlo), maskf(Z[0][2], mlo),
          Z[0][3], Z[1][0], Z[1][1], Z[1][2], Z[1][3], Z[2][0], Z[2][1],
          maskf(Z[2][2], mhi), maskf(Z[2][3], mhi), maskf(ze, mhi)};
      const float xx[7] = {X[0][0], X[0][1], X[0][2], X[0][3],
                           X[1][0], X[1][1], X[1][2]};
      const float wv[7] = {wa[0], wa[1], wa[2], wa[3], wb[1], wb[2], wb[3]};
#pragma unroll
      for (int i = 0; i < 7; ++i)
#pragma unroll
        for (int dx = 0; dx < 7; ++dx)
          acc[dx][i] = fmaf(wv[dx], xx[i] * zz[i + dx], acc[dx][i]);
    }
  };

  // prologue: channels 0,1,2 -> S0,S1,S2; weights(0) -> WA
  loadZX(Z0, z0e, X0, 0);
  loadZX(Z1, z1e, X1, 1);
  loadZX(Z2, z2e, X2, 2);
  loadW(WAa, WAb, 0);

  // main loop: no barriers, no LDS; loads for c+3 overlap compute of c.
#pragma unroll 1
  for (int cc = 0; cc < C; cc += 4) {
    loadZX(Z3, z3e, X3, cc + 3); loadW(WBa, WBb, cc + 1); compute(Z0, z0e, X0, WAa, WAb);
    loadZX(Z0, z0e, X0, cc + 4); loadW(WAa, WAb, cc + 2); compute(Z1, z1e, X1, WBa, WBb);
    loadZX(Z1, z1e, X1, cc + 5); loadW(WBa, WBb, cc + 3); compute(Z2, z2e, X2, WAa, WAb);
    loadZX(Z2, z2e, X2, cc + 6); loadW(WAa, WAb, cc + 4); compute(Z3, z3e, X3, WBa, WBb);
  }

  // ---- coalesced write-out via LDS transpose (7 phases); fold 1/64 ----
  const float s = 1.0f / 64.0f;
#pragma unroll 1
  for (int ph = 0; ph < 7; ++ph) {
    __syncthreads();
    if (dy == ph) {
#pragma unroll
      for (int dx = 0; dx < 7; ++dx)
#pragma unroll
        for (int i = 0; i < 7; ++i)
          obuf[(dx * ROWS + r) * W + q * 7 + i] = acc[dx][i] * s;
    }
    __syncthreads();
#pragma unroll
    for (int mi = 0; mi < 7; ++mi) {
      const int m   = tid + mi * NTHR;
      const int dxl = m / (ROWS * W);
      const int pos = m - dxl * (ROWS * W);
      const int ch  = ph * 7 + dxl;
      out[((size_t)(b * 49 + ch) * T + t) * SLICE + (size_t)h0 * W + pos] =
          obuf[m];
    }
  }
}

}  // namespace

extern "C" void kernel_launch(void* const* d_in, const int* in_sizes, int n_in,
                              void* d_out, int out_size, void* d_ws, size_t ws_size,
                              hipStream_t stream) {
  const float* x  = (const float*)d_in[0];
  const float* fw = (const float*)d_in[1];
  float* out      = (float*)d_out;
  corr_fwd<<<NBLK, NTHR, 0, stream>>>(x, fw, out);
}